// Round 8
// baseline (363.139 us; speedup 1.0000x reference)
//
#include <hip/hip_runtime.h>

// B=2, L=2048, D=1024, H=16, Hd=64, no causal mask. Inputs f32 (device-sniffed).

#define D_MODEL 1024
#define NH 16
#define HD 64
#define BATCH 2
#define SEQ 2048
#define MROWS (BATCH*SEQ)   // 4096

typedef unsigned short u16;
typedef __bf16 bf16x8 __attribute__((ext_vector_type(8)));
typedef float f32x4 __attribute__((ext_vector_type(4)));

__device__ __forceinline__ u16 f2bf(float f){
    __bf16 h = (__bf16)f;                    // hw v_cvt (RNE) on gfx950
    return __builtin_bit_cast(u16, h);
}
__device__ __forceinline__ float fast_exp2(float x){ return __builtin_amdgcn_exp2f(x); }

// async global->LDS, 16B per lane (m97 pattern).
__device__ __forceinline__ void stage16(const void* g, void* l){
#if __has_builtin(__builtin_amdgcn_global_load_lds)
    __builtin_amdgcn_global_load_lds(
        (__attribute__((address_space(1))) void*)(unsigned long long)(g),
        (__attribute__((address_space(3))) void*)(unsigned int)(unsigned long long)(l),
        16, 0, 0);
#else
    *(uint4*)l = *(const uint4*)g;
#endif
}

// f32-vs-bf16 sniff on a pristine input buffer (deterministic, graph-safe).
__device__ __forceinline__ int detect_f32_block(const u16* q, int tid){
    __shared__ int flag;
    if (tid < 64){
        unsigned e = (q[2*tid]>>7)&0xFFu;
        bool hit = (e>=115u)&&(e<=132u);
        unsigned long long m = __ballot(hit);
        if (tid==0) flag = (__popcll(m) < 32) ? 1 : 0;
    }
    __syncthreads();
    return flag;
}

// ---------------------------------------------------------------------------
// One launch converts q,k,v,Wq,Wk,Wv,Wo into contiguous bf16 ws regions.
// ---------------------------------------------------------------------------
__global__ __launch_bounds__(256)
void convert_all(const u16* __restrict__ q, const u16* __restrict__ k,
                 const u16* __restrict__ v, const u16* __restrict__ Wq,
                 const u16* __restrict__ Wk, const u16* __restrict__ Wv,
                 const u16* __restrict__ Wo, u16* __restrict__ dst)
{
    int isf32 = detect_f32_block(q, threadIdx.x);
    int bid = blockIdx.x;
    const u16* src; int lb;
    if      (bid < 4096)  { src=q;  lb=bid; }
    else if (bid < 8192)  { src=k;  lb=bid-4096; }
    else if (bid < 12288) { src=v;  lb=bid-8192; }
    else if (bid < 13312) { src=Wq; lb=bid-12288; }
    else if (bid < 14336) { src=Wk; lb=bid-13312; }
    else if (bid < 15360) { src=Wv; lb=bid-14336; }
    else                  { src=Wo; lb=bid-15360; }
    size_t so = (size_t)lb*1024 + threadIdx.x*4;
    size_t dofs = (size_t)bid*1024 + threadIdx.x*4;
    if (isf32){
        float4 x = *(const float4*)((const float*)src + so);
        ushort4 o; o.x=f2bf(x.x); o.y=f2bf(x.y); o.z=f2bf(x.z); o.w=f2bf(x.w);
        *(ushort4*)(dst+dofs) = o;
    } else {
        *(ushort4*)(dst+dofs) = *(const ushort4*)(src+so);
    }
}

// ---------------------------------------------------------------------------
// Fused Q/K/V projection GEMM (z selects input+weight+output). m97 structure,
// bf16 inputs (converted), async staging.
// z<2 -> split-head [B,H,L,HD]; z==2 -> transposed [B,H,HD,L] for PV.
// ---------------------------------------------------------------------------
__global__ __launch_bounds__(256)
void gemm_qkv(const u16* __restrict__ qb, const u16* __restrict__ kb,
              const u16* __restrict__ vb, const u16* __restrict__ Wqb,
              const u16* __restrict__ Wkb, const u16* __restrict__ Wvb,
              u16* __restrict__ Qh, u16* __restrict__ Kh, u16* __restrict__ Vt)
{
    const int K = 1024;
    __shared__ __align__(16) u16 lA[128*32];
    __shared__ __align__(16) u16 lB[128*32];
    const int z = blockIdx.z;
    const u16* A  = (z==0)? qb  : (z==1)? kb  : vb;
    const u16* Bt = (z==0)? Wqb : (z==1)? Wkb : Wvb;

    const int tid  = threadIdx.x;
    const int wid  = tid>>6, lane = tid&63;
    const int quad = lane>>4, l16 = lane&15;
    const int wm = (wid>>1)*64, wn = (wid&1)*64;
    const int row0 = blockIdx.y*128, col0 = blockIdx.x*128;

    f32x4 acc[4][4];
    #pragma unroll
    for (int i=0;i<4;i++)
        #pragma unroll
        for (int j=0;j<4;j++) acc[i][j] = (f32x4){0.f,0.f,0.f,0.f};

    for (int k0=0; k0<K; k0+=32){
        #pragma unroll
        for (int s=0;s<2;s++){
            int c = tid + s*256;
            int r = c>>2, cc = (c&3)*8;
            stage16(&A [(size_t)(row0+r)*K + k0 + cc], &lA[c*8]);
            stage16(&Bt[(size_t)(col0+r)*K + k0 + cc], &lB[c*8]);
        }
        __syncthreads();
        bf16x8 af[4], bfr[4];
        #pragma unroll
        for (int mi=0;mi<4;mi++) af[mi]  = *(const bf16x8*)&lA[(wm+mi*16+l16)*32 + quad*8];
        #pragma unroll
        for (int ni=0;ni<4;ni++) bfr[ni] = *(const bf16x8*)&lB[(wn+ni*16+l16)*32 + quad*8];
        #pragma unroll
        for (int mi=0;mi<4;mi++)
            #pragma unroll
            for (int ni=0;ni<4;ni++)
                acc[mi][ni] = __builtin_amdgcn_mfma_f32_16x16x32_bf16(af[mi], bfr[ni], acc[mi][ni], 0,0,0);
        __syncthreads();
    }

    u16* Csh = (z==0)? Qh : Kh;
    #pragma unroll
    for (int mi=0;mi<4;mi++){
        #pragma unroll
        for (int ni=0;ni<4;ni++){
            int col = col0 + wn + ni*16 + l16;
            #pragma unroll
            for (int r=0;r<4;r++){
                int row = row0 + wm + mi*16 + quad*4 + r;
                u16 o = f2bf(acc[mi][ni][r]);
                int b = row>>11, i = row&2047, h = col>>6, d = col&63;
                if (z<2) Csh[((((size_t)(b*NH+h))*SEQ + i)<<6) + d] = o;
                else     Vt[((size_t)((b*NH+h)*HD + d))*SEQ + i] = o;
            }
        }
    }
}

// ---------------------------------------------------------------------------
// Output projection: C = ctx * Wo^T (bf16 converted). 64x128 tiles, 512 blocks.
// ---------------------------------------------------------------------------
__global__ __launch_bounds__(256)
void gemm_out(const u16* __restrict__ A, const u16* __restrict__ Bt,
              void* __restrict__ Cv, const u16* __restrict__ qref)
{
    const int K = 1024, N = 1024;
    int outf32 = detect_f32_block(qref, threadIdx.x);
    __shared__ __align__(16) u16 lA[64*32];
    __shared__ __align__(16) u16 lB[128*32];
    const int tid  = threadIdx.x;
    const int wid  = tid>>6, lane = tid&63;
    const int quad = lane>>4, l16 = lane&15;
    const int wm = (wid>>1)*32, wn = (wid&1)*64;
    const int row0 = blockIdx.y*64, col0 = blockIdx.x*128;

    f32x4 acc[2][4];
    #pragma unroll
    for (int i=0;i<2;i++)
        #pragma unroll
        for (int j=0;j<4;j++) acc[i][j] = (f32x4){0.f,0.f,0.f,0.f};

    for (int k0=0; k0<K; k0+=32){
        {   // A: 256 chunks (1/thread)
            int r = tid>>2, cc = (tid&3)*8;
            stage16(&A[(size_t)(row0+r)*K + k0 + cc], &lA[tid*8]);
        }
        #pragma unroll
        for (int s=0;s<2;s++){   // B: 512 chunks
            int c = tid + s*256;
            int r = c>>2, cc = (c&3)*8;
            stage16(&Bt[(size_t)(col0+r)*K + k0 + cc], &lB[c*8]);
        }
        __syncthreads();
        bf16x8 af[2], bfr[4];
        #pragma unroll
        for (int mi=0;mi<2;mi++) af[mi]  = *(const bf16x8*)&lA[(wm+mi*16+l16)*32 + quad*8];
        #pragma unroll
        for (int ni=0;ni<4;ni++) bfr[ni] = *(const bf16x8*)&lB[(wn+ni*16+l16)*32 + quad*8];
        #pragma unroll
        for (int mi=0;mi<2;mi++)
            #pragma unroll
            for (int ni=0;ni<4;ni++)
                acc[mi][ni] = __builtin_amdgcn_mfma_f32_16x16x32_bf16(af[mi], bfr[ni], acc[mi][ni], 0,0,0);
        __syncthreads();
    }

    #pragma unroll
    for (int mi=0;mi<2;mi++){
        #pragma unroll
        for (int ni=0;ni<4;ni++){
            int col = col0 + wn + ni*16 + l16;
            #pragma unroll
            for (int r=0;r<4;r++){
                int row = row0 + wm + mi*16 + quad*4 + r;
                float f = acc[mi][ni][r];
                if (outf32) ((float*)Cv)[(size_t)row*N + col] = f;
                else        ((u16*)Cv)[(size_t)row*N + col] = f2bf(f);
            }
        }
    }
}

// ---------------------------------------------------------------------------
// Flash attention v5: in-block K-split. 512 threads = 8 waves; waves 0-3
// (group 0) process keys 0..1023, waves 4-7 (group 1) keys 1024..2047, each
// wave keeping attn3's verified 32-row (mi=2) structure. Fixed-max softmax
// makes partials additive: O=O0+O1, l=l0+l1, merged once through LDS.
// Single-buffered per-group K/V tiles + VGPR prefetch; 2 barriers/step,
// 16 steps. LDS ~65KB -> 2 blocks/CU = 16 waves/CU.
// ---------------------------------------------------------------------------
#define KVT 4096
#define SW(row, c8) ((row)*64 + ((((c8) ^ ((row)&7)))*8))

__global__ __launch_bounds__(512, 4)
void attn5(const u16* __restrict__ Qh, const u16* __restrict__ Kh,
           const u16* __restrict__ Vt, const int* __restrict__ mask,
           u16* __restrict__ ctx)
{
    __shared__ __align__(16) u16 lk[2*KVT];     // [group][64 key][64 d] swizzled
    __shared__ __align__(16) u16 lv[2*KVT];     // [group][64 d][64 key] swizzled
    __shared__ __align__(16) u16 lps[256*64];   // Q stage (rows 0-127); P bands (8 waves x 32 rows); merge buf (f32 128x64)
    __shared__ float lO[128];
    __shared__ unsigned mb[64];                 // 2048-bit key mask

    const int id = blockIdx.x;                  // 512 blocks
    const int bh = (id&7)*4 + (id>>7);          // 4 heads per XCD
    const int qb = (id>>3)&15;
    const int b = bh>>4, h = bh&15;
    const int i0 = qb*128;
    const int tid = threadIdx.x;
    const int wv = tid>>6, lane = tid&63;
    const int g = wv>>2, w4 = wv&3;             // key-split group, wave-in-group
    const int quad = lane>>4, l16 = lane&15;

    const u16* Qp  = Qh + ((size_t)bh*SEQ + i0)*HD;
    const u16* Kp  = Kh + (size_t)bh*SEQ*HD;
    const u16* Vtp = Vt + (size_t)bh*HD*SEQ;
    const int* mp  = mask + b*SEQ;

    // ---- prefetch step-0 K/V tiles (both groups) into VGPRs ----
    uint4 gk[2], gv[2];
    #pragma unroll
    for (int s=0;s<2;s++){
        int c = tid + s*512;                 // 1024 chunks: [gg][r][c8]
        int gg = c>>9, l = c&511, r = l>>3, c8 = l&7;
        int j0g = gg*1024;
        gk[s] = *(const uint4*)&Kp[(size_t)(j0g + r)*HD + c8*8];
        gv[s] = *(const uint4*)&Vtp[(size_t)r*SEQ + j0g + c8*8];
    }

    // ---- stage Q (128x64 swizzled) + mask bits ----
    #pragma unroll
    for (int s=0;s<2;s++){
        int c = tid + s*512;                 // 1024 chunks
        int r = c>>3, c8 = c&7;
        *(uint4*)&lps[SW(r,c8)] = *(const uint4*)&Qp[(size_t)r*HD + c8*8];
    }
    if (tid < 64){
        unsigned w = 0;
        #pragma unroll 8
        for (int i=0;i<32;i++) w |= (mp[tid*32+i] ? 1u:0u) << i;
        mb[tid] = w;
    }
    __syncthreads();

    // per-wave Q fragments (both groups read the same 128 q-rows)
    bf16x8 aq[2][2];
    #pragma unroll
    for (int mi=0;mi<2;mi++)
        #pragma unroll
        for (int kk=0;kk<2;kk++)
            aq[mi][kk] = *(const bf16x8*)&lps[SW(w4*32+mi*16+l16, kk*4+quad)];
    __syncthreads();   // aq reads done before anyone's P writes reuse lps

    const u16* lkc = lk + g*KVT;
    const u16* lvc = lv + g*KVT;
    const int prow0 = wv*32;                 // wave-private 32x64 P band

    u16 onebits[8] = {0x3F80,0x3F80,0x3F80,0x3F80,0x3F80,0x3F80,0x3F80,0x3F80};
    bf16x8 bones = *(bf16x8*)onebits;

    f32x4 Oacc[2][4];
    f32x4 Lacc[2];
    #pragma unroll
    for (int mi=0;mi<2;mi++){
        Lacc[mi] = (f32x4){0.f,0.f,0.f,0.f};
        #pragma unroll
        for (int dn=0;dn<4;dn++) Oacc[mi][dn] = (f32x4){0.f,0.f,0.f,0.f};
    }

    const float SC = 0.125f * 1.44269504f;   // 1/sqrt(64) * log2(e)

    for (int t=0; t<16; t++){
        // ---- commit prefetched tiles (both groups) ----
        #pragma unroll
        for (int s=0;s<2;s++){
            int c = tid + s*512;
            int gg = c>>9, l = c&511, r = l>>3, c8 = l&7;
            *(uint4*)&lk[gg*KVT + SW(r,c8)] = gk[s];
            *(uint4*)&lv[gg*KVT + SW(r,c8)] = gv[s];
        }
        __syncthreads();   // staged tiles visible

        // ---- prefetch next step ----
        if (t < 15){
            #pragma unroll
            for (int s=0;s<2;s++){
                int c = tid + s*512;
                int gg = c>>9, l = c&511, r = l>>3, c8 = l&7;
                int j0g = gg*1024 + (t+1)*64;
                gk[s] = *(const uint4*)&Kp[(size_t)(j0g + r)*HD + c8*8];
                gv[s] = *(const uint4*)&Vtp[(size_t)r*SEQ + j0g + c8*8];
            }
        }

        // ---- S = Q K^T (this group's tile) ----
        f32x4 sfr[2][4];
        #pragma unroll
        for (int jn=0;jn<4;jn++){
            bf16x8 bk0 = *(const bf16x8*)&lkc[SW(jn*16+l16, quad)];
            bf16x8 bk1 = *(const bf16x8*)&lkc[SW(jn*16+l16, 4+quad)];
            #pragma unroll
            for (int mi=0;mi<2;mi++){
                f32x4 a0 = (f32x4){0.f,0.f,0.f,0.f};
                a0 = __builtin_amdgcn_mfma_f32_16x16x32_bf16(aq[mi][0], bk0, a0, 0,0,0);
                a0 = __builtin_amdgcn_mfma_f32_16x16x32_bf16(aq[mi][1], bk1, a0, 0,0,0);
                sfr[mi][jn] = a0;
            }
        }

        // ---- P = exp2(S*SC + bias) -> bf16 wave-private LDS ----
        int tg = g*16 + t;
        unsigned mw0 = mb[tg*2], mw1 = mb[tg*2+1];
        #pragma unroll
        for (int jn=0;jn<4;jn++){
            unsigned mw = (jn<2)? mw0 : mw1;
            int sh = (jn&1)*16 + l16;
            float bias = ((mw>>sh)&1u) ? 0.f : -1.5e9f;
            int c8 = jn*2 + (l16>>3), cb = l16&7;
            #pragma unroll
            for (int mi=0;mi<2;mi++){
                #pragma unroll
                for (int r=0;r<4;r++){
                    float p = fast_exp2(sfr[mi][jn][r]*SC + bias);
                    lps[SW(prow0+mi*16+quad*4+r, c8) + cb] = f2bf(p);
                }
            }
        }
        // same-wave LDS RAW: compiler inserts lgkmcnt wait
        bf16x8 ap[2][2];
        #pragma unroll
        for (int mi=0;mi<2;mi++)
            #pragma unroll
            for (int kk=0;kk<2;kk++)
                ap[mi][kk] = *(const bf16x8*)&lps[SW(prow0+mi*16+l16, kk*4+quad)];

        // ---- O += P V ; l += P * 1 ----
        #pragma unroll
        for (int dn=0;dn<4;dn++){
            #pragma unroll
            for (int kk=0;kk<2;kk++){
                bf16x8 bv = *(const bf16x8*)&lvc[SW(dn*16+l16, kk*4+quad)];
                #pragma unroll
                for (int mi=0;mi<2;mi++)
                    Oacc[mi][dn] = __builtin_amdgcn_mfma_f32_16x16x32_bf16(ap[mi][kk], bv, Oacc[mi][dn], 0,0,0);
            }
        }
        #pragma unroll
        for (int mi=0;mi<2;mi++)
            #pragma unroll
            for (int kk=0;kk<2;kk++)
                Lacc[mi] = __builtin_amdgcn_mfma_f32_16x16x32_bf16(ap[mi][kk], bones, Lacc[mi], 0,0,0);

        __syncthreads();   // all reads of lk/lv done before next commit
    }

    // ---- merge group 1 into group 0 via LDS, then write ctx ----
    float* lpf = (float*)lps;                // 128 rows x 64 d f32 (32KB)
    if (g==1){
        #pragma unroll
        for (int mi=0;mi<2;mi++){
            #pragma unroll
            for (int dn=0;dn<4;dn++){
                #pragma unroll
                for (int r=0;r<4;r++)
                    lpf[(w4*32+mi*16+quad*4+r)*64 + dn*16+l16] = Oacc[mi][dn][r];
            }
            if (l16==0){
                #pragma unroll
                for (int r=0;r<4;r++) lO[w4*32+mi*16+quad*4+r] = Lacc[mi][r];
            }
        }
    }
    __syncthreads();
    if (g==0){
        #pragma unroll
        for (int mi=0;mi<2;mi++){
            f32x4 rl;
            #pragma unroll
            for (int r=0;r<4;r++){
                int row = w4*32+mi*16+quad*4+r;
                rl[r] = 1.0f / (Lacc[mi][r] + lO[row]);
            }
            #pragma unroll
            for (int dn=0;dn<4;dn++){
                int col = h*HD + dn*16 + l16;
                #pragma unroll
                for (int r=0;r<4;r++){
                    int row = w4*32+mi*16+quad*4+r;
                    float o = Oacc[mi][dn][r] + lpf[row*64 + dn*16+l16];
                    int i = i0 + row;
                    ctx[((size_t)(b*SEQ + i))*D_MODEL + col] = f2bf(o*rl[r]);
                }
            }
        }
    }
}

// ---------------------------------------------------------------------------
extern "C" void kernel_launch(void* const* d_in, const int* in_sizes, int n_in,
                              void* d_out, int out_size, void* d_ws, size_t ws_size,
                              hipStream_t stream)
{
    (void)in_sizes; (void)n_in; (void)out_size; (void)ws_size;
    const u16* q    = (const u16*)d_in[0];
    const u16* k    = (const u16*)d_in[1];
    const u16* v    = (const u16*)d_in[2];
    const int* mask = (const int*)d_in[3];
    const u16* Wq   = (const u16*)d_in[4];
    const u16* Wk   = (const u16*)d_in[5];
    const u16* Wv   = (const u16*)d_in[6];
    const u16* Wo   = (const u16*)d_in[7];

    const size_t TEN = (size_t)MROWS * D_MODEL;   // 4 Mi elements
    const size_t WEL = (size_t)D_MODEL * D_MODEL; // 1 Mi
    u16* qb  = (u16*)d_ws;        // converted bf16 (convert_all order)
    u16* kb  = qb + TEN;
    u16* vb  = kb + TEN;
    u16* Wqb = vb + TEN;
    u16* Wkb = Wqb + WEL;
    u16* Wvb = Wkb + WEL;
    u16* Wob = Wvb + WEL;
    u16* Qh  = Wob + WEL;         // [B,H,L,HD]
    u16* Kh  = Qh + TEN;
    u16* Vtr = Kh + TEN;          // [B,H,HD,L]
    u16* ctx = Vtr + TEN;         // [B,L,D]  -> 64 MiB total

    convert_all<<<dim3(16384), dim3(256), 0, stream>>>(q,k,v,Wq,Wk,Wv,Wo, qb);
    gemm_qkv<<<dim3(8,32,3), dim3(256), 0, stream>>>(qb,kb,vb, Wqb,Wkb,Wvb, Qh,Kh,Vtr);
    attn5<<<dim3(512), dim3(512), 0, stream>>>(Qh, Kh, Vtr, mask, ctx);
    gemm_out<<<dim3(8,64), dim3(256), 0, stream>>>(ctx, Wob, d_out, q);
}

// Round 9
// 255.059 us; speedup vs baseline: 1.4237x; 1.4237x over previous
//
#include <hip/hip_runtime.h>

// B=2, L=2048, D=1024, H=16, Hd=64, no causal mask. Inputs f32 (device-sniffed).
// NOTE (R8 post-mortem): __launch_bounds__(512,4) caused VGPR=64 -> spills ->
// 313MB scratch writes. Keep 256-thread attention blocks, no min-waves clamp.

#define D_MODEL 1024
#define NH 16
#define HD 64
#define BATCH 2
#define SEQ 2048
#define MROWS (BATCH*SEQ)   // 4096

typedef unsigned short u16;
typedef __bf16 bf16x8 __attribute__((ext_vector_type(8)));
typedef float f32x4 __attribute__((ext_vector_type(4)));

#if __has_builtin(__builtin_amdgcn_mfma_f32_16x16x16bf16_1k)
#define HAVE_M16 1
typedef short s16x4 __attribute__((ext_vector_type(4)));
#endif

__device__ __forceinline__ u16 f2bf(float f){
    __bf16 h = (__bf16)f;                    // hw v_cvt (RNE) on gfx950
    return __builtin_bit_cast(u16, h);
}
__device__ __forceinline__ float fast_exp2(float x){ return __builtin_amdgcn_exp2f(x); }

// async global->LDS, 16B per lane (m97 pattern).
__device__ __forceinline__ void stage16(const void* g, void* l){
#if __has_builtin(__builtin_amdgcn_global_load_lds)
    __builtin_amdgcn_global_load_lds(
        (__attribute__((address_space(1))) void*)(unsigned long long)(g),
        (__attribute__((address_space(3))) void*)(unsigned int)(unsigned long long)(l),
        16, 0, 0);
#else
    *(uint4*)l = *(const uint4*)g;
#endif
}

// f32-vs-bf16 sniff on a pristine input buffer (deterministic, graph-safe).
__device__ __forceinline__ int detect_f32_block(const u16* q, int tid){
    __shared__ int flag;
    if (tid < 64){
        unsigned e = (q[2*tid]>>7)&0xFFu;
        bool hit = (e>=115u)&&(e<=132u);
        unsigned long long m = __ballot(hit);
        if (tid==0) flag = (__popcll(m) < 32) ? 1 : 0;
    }
    __syncthreads();
    return flag;
}

// ---------------------------------------------------------------------------
// One launch converts q,k,v,Wq,Wk,Wv,Wo into contiguous bf16 ws regions.
// ---------------------------------------------------------------------------
__global__ __launch_bounds__(256)
void convert_all(const u16* __restrict__ q, const u16* __restrict__ k,
                 const u16* __restrict__ v, const u16* __restrict__ Wq,
                 const u16* __restrict__ Wk, const u16* __restrict__ Wv,
                 const u16* __restrict__ Wo, u16* __restrict__ dst)
{
    int isf32 = detect_f32_block(q, threadIdx.x);
    int bid = blockIdx.x;
    const u16* src; int lb;
    if      (bid < 4096)  { src=q;  lb=bid; }
    else if (bid < 8192)  { src=k;  lb=bid-4096; }
    else if (bid < 12288) { src=v;  lb=bid-8192; }
    else if (bid < 13312) { src=Wq; lb=bid-12288; }
    else if (bid < 14336) { src=Wk; lb=bid-13312; }
    else if (bid < 15360) { src=Wv; lb=bid-14336; }
    else                  { src=Wo; lb=bid-15360; }
    size_t so = (size_t)lb*1024 + threadIdx.x*4;
    size_t dofs = (size_t)bid*1024 + threadIdx.x*4;
    if (isf32){
        float4 x = *(const float4*)((const float*)src + so);
        ushort4 o; o.x=f2bf(x.x); o.y=f2bf(x.y); o.z=f2bf(x.z); o.w=f2bf(x.w);
        *(ushort4*)(dst+dofs) = o;
    } else {
        *(ushort4*)(dst+dofs) = *(const ushort4*)(src+so);
    }
}

// ---------------------------------------------------------------------------
// Fused Q/K/V projection GEMM (z selects input+weight+output). m97 structure.
// z<2 -> split-head [B,H,L,HD]; z==2 -> transposed [B,H,HD,L] for PV.
// ---------------------------------------------------------------------------
__global__ __launch_bounds__(256)
void gemm_qkv(const u16* __restrict__ qb, const u16* __restrict__ kb,
              const u16* __restrict__ vb, const u16* __restrict__ Wqb,
              const u16* __restrict__ Wkb, const u16* __restrict__ Wvb,
              u16* __restrict__ Qh, u16* __restrict__ Kh, u16* __restrict__ Vt)
{
    const int K = 1024;
    __shared__ __align__(16) u16 lA[128*32];
    __shared__ __align__(16) u16 lB[128*32];
    const int z = blockIdx.z;
    const u16* A  = (z==0)? qb  : (z==1)? kb  : vb;
    const u16* Bt = (z==0)? Wqb : (z==1)? Wkb : Wvb;

    const int tid  = threadIdx.x;
    const int wid  = tid>>6, lane = tid&63;
    const int quad = lane>>4, l16 = lane&15;
    const int wm = (wid>>1)*64, wn = (wid&1)*64;
    const int row0 = blockIdx.y*128, col0 = blockIdx.x*128;

    f32x4 acc[4][4];
    #pragma unroll
    for (int i=0;i<4;i++)
        #pragma unroll
        for (int j=0;j<4;j++) acc[i][j] = (f32x4){0.f,0.f,0.f,0.f};

    for (int k0=0; k0<K; k0+=32){
        #pragma unroll
        for (int s=0;s<2;s++){
            int c = tid + s*256;
            int r = c>>2, cc = (c&3)*8;
            stage16(&A [(size_t)(row0+r)*K + k0 + cc], &lA[c*8]);
            stage16(&Bt[(size_t)(col0+r)*K + k0 + cc], &lB[c*8]);
        }
        __syncthreads();
        bf16x8 af[4], bfr[4];
        #pragma unroll
        for (int mi=0;mi<4;mi++) af[mi]  = *(const bf16x8*)&lA[(wm+mi*16+l16)*32 + quad*8];
        #pragma unroll
        for (int ni=0;ni<4;ni++) bfr[ni] = *(const bf16x8*)&lB[(wn+ni*16+l16)*32 + quad*8];
        #pragma unroll
        for (int mi=0;mi<4;mi++)
            #pragma unroll
            for (int ni=0;ni<4;ni++)
                acc[mi][ni] = __builtin_amdgcn_mfma_f32_16x16x32_bf16(af[mi], bfr[ni], acc[mi][ni], 0,0,0);
        __syncthreads();
    }

    u16* Csh = (z==0)? Qh : Kh;
    #pragma unroll
    for (int mi=0;mi<4;mi++){
        #pragma unroll
        for (int ni=0;ni<4;ni++){
            int col = col0 + wn + ni*16 + l16;
            #pragma unroll
            for (int r=0;r<4;r++){
                int row = row0 + wm + mi*16 + quad*4 + r;
                u16 o = f2bf(acc[mi][ni][r]);
                int b = row>>11, i = row&2047, h = col>>6, d = col&63;
                if (z<2) Csh[((((size_t)(b*NH+h))*SEQ + i)<<6) + d] = o;
                else     Vt[((size_t)((b*NH+h)*HD + d))*SEQ + i] = o;
            }
        }
    }
}

// ---------------------------------------------------------------------------
// Output projection: C = ctx * Wo^T (bf16 converted). 64x128 tiles, 512 blocks.
// ---------------------------------------------------------------------------
__global__ __launch_bounds__(256)
void gemm_out(const u16* __restrict__ A, const u16* __restrict__ Bt,
              void* __restrict__ Cv, const u16* __restrict__ qref)
{
    const int K = 1024, N = 1024;
    int outf32 = detect_f32_block(qref, threadIdx.x);
    __shared__ __align__(16) u16 lA[64*32];
    __shared__ __align__(16) u16 lB[128*32];
    const int tid  = threadIdx.x;
    const int wid  = tid>>6, lane = tid&63;
    const int quad = lane>>4, l16 = lane&15;
    const int wm = (wid>>1)*32, wn = (wid&1)*64;
    const int row0 = blockIdx.y*64, col0 = blockIdx.x*128;

    f32x4 acc[2][4];
    #pragma unroll
    for (int i=0;i<2;i++)
        #pragma unroll
        for (int j=0;j<4;j++) acc[i][j] = (f32x4){0.f,0.f,0.f,0.f};

    for (int k0=0; k0<K; k0+=32){
        {
            int r = tid>>2, cc = (tid&3)*8;
            stage16(&A[(size_t)(row0+r)*K + k0 + cc], &lA[tid*8]);
        }
        #pragma unroll
        for (int s=0;s<2;s++){
            int c = tid + s*256;
            int r = c>>2, cc = (c&3)*8;
            stage16(&Bt[(size_t)(col0+r)*K + k0 + cc], &lB[c*8]);
        }
        __syncthreads();
        bf16x8 af[2], bfr[4];
        #pragma unroll
        for (int mi=0;mi<2;mi++) af[mi]  = *(const bf16x8*)&lA[(wm+mi*16+l16)*32 + quad*8];
        #pragma unroll
        for (int ni=0;ni<4;ni++) bfr[ni] = *(const bf16x8*)&lB[(wn+ni*16+l16)*32 + quad*8];
        #pragma unroll
        for (int mi=0;mi<2;mi++)
            #pragma unroll
            for (int ni=0;ni<4;ni++)
                acc[mi][ni] = __builtin_amdgcn_mfma_f32_16x16x32_bf16(af[mi], bfr[ni], acc[mi][ni], 0,0,0);
        __syncthreads();
    }

    #pragma unroll
    for (int mi=0;mi<2;mi++){
        #pragma unroll
        for (int ni=0;ni<4;ni++){
            int col = col0 + wn + ni*16 + l16;
            #pragma unroll
            for (int r=0;r<4;r++){
                int row = row0 + wm + mi*16 + quad*4 + r;
                float f = acc[mi][ni][r];
                if (outf32) ((float*)Cv)[(size_t)row*N + col] = f;
                else        ((u16*)Cv)[(size_t)row*N + col] = f2bf(f);
            }
        }
    }
}

// ---------------------------------------------------------------------------
// Flash attention v6: S^T trick removes the P LDS round-trip.
// Compute S^T = K Q^T via mfma_16x16x32 (operands swapped; both frags load
// exactly as in attn3). C-layout of S^T: lane l16 = q, regs = keys quad*4+r —
// which IS the A-fragment layout of mfma_f32_16x16x16_bf16 (k = 4*quad+j).
// So P = exp2(S^T) packs straight into K=16 PV A-frags; B = Vt b64 reads.
// 256 threads, 4 waves x 32 q-rows, dbuf K-tiles, 1 barrier/tile, bitmask,
// ones-MFMA l. LDS ~48KB -> 3 blocks/CU.
// ---------------------------------------------------------------------------
#define KVT 4096
#define SW(row, c8) ((row)*64 + ((((c8) ^ ((row)&7)))*8))

#ifdef HAVE_M16
__global__ __launch_bounds__(256)
void attn6(const u16* __restrict__ Qh, const u16* __restrict__ Kh,
           const u16* __restrict__ Vt, const int* __restrict__ mask,
           u16* __restrict__ ctx)
{
    __shared__ __align__(16) u16 lk[2*KVT];
    __shared__ __align__(16) u16 lv[2*KVT];
    __shared__ __align__(16) u16 lps[128*64];   // Q staging only
    __shared__ unsigned mb[64];                 // 2048-bit key mask

    const int id = blockIdx.x;                  // 512 blocks
    const int bh = (id&7)*4 + (id>>7);          // 4 heads per XCD
    const int qb = (id>>3)&15;
    const int b = bh>>4, h = bh&15;
    const int i0 = qb*128;
    const int tid = threadIdx.x;
    const int wv = tid>>6, lane = tid&63;
    const int quad = lane>>4, l16 = lane&15;

    const u16* Qp  = Qh + ((size_t)bh*SEQ + i0)*HD;
    const u16* Kp  = Kh + (size_t)bh*SEQ*HD;
    const u16* Vtp = Vt + (size_t)bh*HD*SEQ;
    const int* mp  = mask + b*SEQ;

    // ---- prologue: Q (128x64 swizzled), mask bits, K/V tile 0 ----
    #pragma unroll
    for (int s=0;s<4;s++){
        int c = tid + s*256;                 // 1024 chunks
        int r = c>>3, c8 = c&7;
        *(uint4*)&lps[SW(r,c8)] = *(const uint4*)&Qp[(size_t)r*HD + c8*8];
    }
    if (tid < 64){
        unsigned w = 0;
        #pragma unroll 8
        for (int i=0;i<32;i++) w |= (mp[tid*32+i] ? 1u:0u) << i;
        mb[tid] = w;
    }
    #pragma unroll
    for (int s=0;s<2;s++){
        int c = tid + s*256;                 // 512 chunks per tile
        int r = c>>3, c8 = c&7;
        *(uint4*)&lk[SW(r,c8)] = *(const uint4*)&Kp[(size_t)r*HD + c8*8];
        *(uint4*)&lv[SW(r,c8)] = *(const uint4*)&Vtp[(size_t)r*SEQ + c8*8];
    }
    __syncthreads();

    // per-wave Q fragments (rows wv*32+mi*16+l16), register-resident
    bf16x8 aq[2][2];
    #pragma unroll
    for (int mi=0;mi<2;mi++)
        #pragma unroll
        for (int kk=0;kk<2;kk++)
            aq[mi][kk] = *(const bf16x8*)&lps[SW(wv*32+mi*16+l16, kk*4+quad)];

    s16x4 bones4 = {0x3F80, 0x3F80, 0x3F80, 0x3F80};   // bf16 1.0 x4

    f32x4 Oacc[2][4];
    f32x4 Lacc[2];
    #pragma unroll
    for (int mi=0;mi<2;mi++){
        Lacc[mi] = (f32x4){0.f,0.f,0.f,0.f};
        #pragma unroll
        for (int dn=0;dn<4;dn++) Oacc[mi][dn] = (f32x4){0.f,0.f,0.f,0.f};
    }

    const float SC = 0.125f * 1.44269504f;   // 1/sqrt(64) * log2(e)

    for (int t=0; t<32; t++){
        const int j0 = t*64;
        const u16* lkc = lk + (t&1)*KVT;
        const u16* lvc = lv + (t&1)*KVT;
        u16* lkn = lk + ((t&1)^1)*KVT;
        u16* lvn = lv + ((t&1)^1)*KVT;

        __syncthreads();

        // prefetch next tile into VGPRs
        uint4 gk[2], gv[2];
        if (t < 31){
            #pragma unroll
            for (int s=0;s<2;s++){
                int c = tid + s*256;
                int r = c>>3, c8 = c&7;
                gk[s] = *(const uint4*)&Kp[(size_t)(j0+64+r)*HD + c8*8];
                gv[s] = *(const uint4*)&Vtp[(size_t)r*SEQ + j0+64 + c8*8];
            }
        }

        // ---- S^T = K Q^T : frag [jn (key16-blk)][mi (q16-blk)] ----
        // lane l16 = q, regs = keys jn*16 + quad*4 + r
        f32x4 sfr[4][2];
        #pragma unroll
        for (int jn=0;jn<4;jn++){
            bf16x8 bk0 = *(const bf16x8*)&lkc[SW(jn*16+l16, quad)];
            bf16x8 bk1 = *(const bf16x8*)&lkc[SW(jn*16+l16, 4+quad)];
            #pragma unroll
            for (int mi=0;mi<2;mi++){
                f32x4 a0 = (f32x4){0.f,0.f,0.f,0.f};
                a0 = __builtin_amdgcn_mfma_f32_16x16x32_bf16(bk0, aq[mi][0], a0, 0,0,0);
                a0 = __builtin_amdgcn_mfma_f32_16x16x32_bf16(bk1, aq[mi][1], a0, 0,0,0);
                sfr[jn][mi] = a0;
            }
        }

        // ---- P = exp2(S*SC + bias) packed directly into K=16 A-frags ----
        unsigned mw0 = mb[t*2], mw1 = mb[t*2+1];
        s16x4 ap16[2][4];   // [mi][kks=jn]
        #pragma unroll
        for (int jn=0;jn<4;jn++){
            unsigned mw = (jn<2)? mw0 : mw1;
            unsigned nib = (mw >> (((jn&1)<<4) + quad*4)) & 0xFu;
            #pragma unroll
            for (int mi=0;mi<2;mi++){
                #pragma unroll
                for (int r=0;r<4;r++){
                    float bias = ((nib>>r)&1u) ? 0.f : -1.5e9f;
                    float p = fast_exp2(sfr[jn][mi][r]*SC + bias);
                    ap16[mi][jn][r] = (short)f2bf(p);
                }
            }
        }

        // ---- O += P V (K=16 MFMAs, B = Vt b64 frags) ; l += P * 1 ----
        #pragma unroll
        for (int kks=0;kks<4;kks++){
            #pragma unroll
            for (int dn=0;dn<4;dn++){
                // B[k=key][n=d]: lane l16 = d (within dn blk), k = kks*16+quad*4+j
                int c8 = kks*2 + (quad>>1);
                s16x4 bv = *(const s16x4*)&lvc[SW(dn*16+l16, c8) + (quad&1)*4];
                #pragma unroll
                for (int mi=0;mi<2;mi++)
                    Oacc[mi][dn] = __builtin_amdgcn_mfma_f32_16x16x16bf16_1k(
                        ap16[mi][kks], bv, Oacc[mi][dn], 0,0,0);
            }
            #pragma unroll
            for (int mi=0;mi<2;mi++)
                Lacc[mi] = __builtin_amdgcn_mfma_f32_16x16x16bf16_1k(
                    ap16[mi][kks], bones4, Lacc[mi], 0,0,0);
        }

        // ---- commit prefetched tile ----
        if (t < 31){
            #pragma unroll
            for (int s=0;s<2;s++){
                int c = tid + s*256;
                int r = c>>3, c8 = c&7;
                *(uint4*)&lkn[SW(r,c8)] = gk[s];
                *(uint4*)&lvn[SW(r,c8)] = gv[s];
            }
        }
    }

    // ---- epilogue: O/l -> ctx [B, L, H*HD] (C-layout rows/cols unchanged) ----
    #pragma unroll
    for (int mi=0;mi<2;mi++){
        f32x4 rl;
        #pragma unroll
        for (int r=0;r<4;r++) rl[r] = 1.0f / Lacc[mi][r];
        #pragma unroll
        for (int dn=0;dn<4;dn++){
            int col = h*HD + dn*16 + l16;
            #pragma unroll
            for (int r=0;r<4;r++){
                int i = i0 + wv*32 + mi*16 + quad*4 + r;
                ctx[((size_t)(b*SEQ + i))*D_MODEL + col] = f2bf(Oacc[mi][dn][r]*rl[r]);
            }
        }
    }
}

#else  // !HAVE_M16 — fallback: round-6 attn3 (P through LDS)

__global__ __launch_bounds__(256)
void attn6(const u16* __restrict__ Qh, const u16* __restrict__ Kh,
           const u16* __restrict__ Vt, const int* __restrict__ mask,
           u16* __restrict__ ctx)
{
    __shared__ __align__(16) u16 lk[2*KVT];
    __shared__ __align__(16) u16 lv[2*KVT];
    __shared__ __align__(16) u16 lps[128*64];
    __shared__ unsigned mb[64];

    const int id = blockIdx.x;
    const int bh = (id&7)*4 + (id>>7);
    const int qb = (id>>3)&15;
    const int b = bh>>4, h = bh&15;
    const int i0 = qb*128;
    const int tid = threadIdx.x;
    const int wv = tid>>6, lane = tid&63;
    const int quad = lane>>4, l16 = lane&15;

    const u16* Qp  = Qh + ((size_t)bh*SEQ + i0)*HD;
    const u16* Kp  = Kh + (size_t)bh*SEQ*HD;
    const u16* Vtp = Vt + (size_t)bh*HD*SEQ;
    const int* mp  = mask + b*SEQ;

    #pragma unroll
    for (int s=0;s<4;s++){
        int c = tid + s*256;
        int r = c>>3, c8 = c&7;
        *(uint4*)&lps[SW(r,c8)] = *(const uint4*)&Qp[(size_t)r*HD + c8*8];
    }
    if (tid < 64){
        unsigned w = 0;
        #pragma unroll 8
        for (int i=0;i<32;i++) w |= (mp[tid*32+i] ? 1u:0u) << i;
        mb[tid] = w;
    }
    #pragma unroll
    for (int s=0;s<2;s++){
        int c = tid + s*256;
        int r = c>>3, c8 = c&7;
        *(uint4*)&lk[SW(r,c8)] = *(const uint4*)&Kp[(size_t)r*HD + c8*8];
        *(uint4*)&lv[SW(r,c8)] = *(const uint4*)&Vtp[(size_t)r*SEQ + c8*8];
    }
    __syncthreads();

    bf16x8 aq[2][2];
    #pragma unroll
    for (int mi=0;mi<2;mi++)
        #pragma unroll
        for (int kk=0;kk<2;kk++)
            aq[mi][kk] = *(const bf16x8*)&lps[SW(wv*32+mi*16+l16, kk*4+quad)];

    const int prow0 = wv*32;
    u16 onebits[8] = {0x3F80,0x3F80,0x3F80,0x3F80,0x3F80,0x3F80,0x3F80,0x3F80};
    bf16x8 bones = *(bf16x8*)onebits;

    f32x4 Oacc[2][4];
    f32x4 Lacc[2];
    #pragma unroll
    for (int mi=0;mi<2;mi++){
        Lacc[mi] = (f32x4){0.f,0.f,0.f,0.f};
        #pragma unroll
        for (int dn=0;dn<4;dn++) Oacc[mi][dn] = (f32x4){0.f,0.f,0.f,0.f};
    }

    const float SC = 0.125f * 1.44269504f;

    for (int t=0; t<32; t++){
        const int j0 = t*64;
        const u16* lkc = lk + (t&1)*KVT;
        const u16* lvc = lv + (t&1)*KVT;
        u16* lkn = lk + ((t&1)^1)*KVT;
        u16* lvn = lv + ((t&1)^1)*KVT;

        __syncthreads();

        uint4 gk[2], gv[2];
        if (t < 31){
            #pragma unroll
            for (int s=0;s<2;s++){
                int c = tid + s*256;
                int r = c>>3, c8 = c&7;
                gk[s] = *(const uint4*)&Kp[(size_t)(j0+64+r)*HD + c8*8];
                gv[s] = *(const uint4*)&Vtp[(size_t)r*SEQ + j0+64 + c8*8];
            }
        }

        f32x4 sfr[2][4];
        #pragma unroll
        for (int jn=0;jn<4;jn++){
            bf16x8 bk0 = *(const bf16x8*)&lkc[SW(jn*16+l16, quad)];
            bf16x8 bk1 = *(const bf16x8*)&lkc[SW(jn*16+l16, 4+quad)];
            #pragma unroll
            for (int mi=0;mi<2;mi++){
                f32x4 a0 = (f32x4){0.f,0.f,0.f,0.f};
                a0 = __builtin_amdgcn_mfma_f32_16x16x32_bf16(aq[mi][0], bk0, a0, 0,0,0);
                a0 = __builtin_amdgcn_mfma_f32_16x16x32_bf16(aq[mi][1], bk1, a0, 0,0,0);
                sfr[mi][jn] = a0;
            }
        }

        unsigned mw0 = mb[t*2], mw1 = mb[t*2+1];
        #pragma unroll
        for (int jn=0;jn<4;jn++){
            unsigned mw = (jn<2)? mw0 : mw1;
            int sh = (jn&1)*16 + l16;
            float bias = ((mw>>sh)&1u) ? 0.f : -1.5e9f;
            int c8 = jn*2 + (l16>>3), cb = l16&7;
            #pragma unroll
            for (int mi=0;mi<2;mi++){
                #pragma unroll
                for (int r=0;r<4;r++){
                    float p = fast_exp2(sfr[mi][jn][r]*SC + bias);
                    lps[SW(prow0+mi*16+quad*4+r, c8) + cb] = f2bf(p);
                }
            }
        }
        bf16x8 ap[2][2];
        #pragma unroll
        for (int mi=0;mi<2;mi++)
            #pragma unroll
            for (int kk=0;kk<2;kk++)
                ap[mi][kk] = *(const bf16x8*)&lps[SW(prow0+mi*16+l16, kk*4+quad)];

        #pragma unroll
        for (int dn=0;dn<4;dn++){
            #pragma unroll
            for (int kk=0;kk<2;kk++){
                bf16x8 bv = *(const bf16x8*)&lvc[SW(dn*16+l16, kk*4+quad)];
                #pragma unroll
                for (int mi=0;mi<2;mi++)
                    Oacc[mi][dn] = __builtin_amdgcn_mfma_f32_16x16x32_bf16(ap[mi][kk], bv, Oacc[mi][dn], 0,0,0);
            }
        }
        #pragma unroll
        for (int mi=0;mi<2;mi++)
            #pragma unroll
            for (int kk=0;kk<2;kk++)
                Lacc[mi] = __builtin_amdgcn_mfma_f32_16x16x32_bf16(ap[mi][kk], bones, Lacc[mi], 0,0,0);

        if (t < 31){
            #pragma unroll
            for (int s=0;s<2;s++){
                int c = tid + s*256;
                int r = c>>3, c8 = c&7;
                *(uint4*)&lkn[SW(r,c8)] = gk[s];
                *(uint4*)&lvn[SW(r,c8)] = gv[s];
            }
        }
    }

    #pragma unroll
    for (int mi=0;mi<2;mi++){
        f32x4 rl;
        #pragma unroll
        for (int r=0;r<4;r++) rl[r] = 1.0f / Lacc[mi][r];
        #pragma unroll
        for (int dn=0;dn<4;dn++){
            int col = h*HD + dn*16 + l16;
            #pragma unroll
            for (int r=0;r<4;r++){
                int i = i0 + wv*32 + mi*16 + quad*4 + r;
                ctx[((size_t)(b*SEQ + i))*D_MODEL + col] = f2bf(Oacc[mi][dn][r]*rl[r]);
            }
        }
    }
}
#endif

// ---------------------------------------------------------------------------
extern "C" void kernel_launch(void* const* d_in, const int* in_sizes, int n_in,
                              void* d_out, int out_size, void* d_ws, size_t ws_size,
                              hipStream_t stream)
{
    (void)in_sizes; (void)n_in; (void)out_size; (void)ws_size;
    const u16* q    = (const u16*)d_in[0];
    const u16* k    = (const u16*)d_in[1];
    const u16* v    = (const u16*)d_in[2];
    const int* mask = (const int*)d_in[3];
    const u16* Wq   = (const u16*)d_in[4];
    const u16* Wk   = (const u16*)d_in[5];
    const u16* Wv   = (const u16*)d_in[6];
    const u16* Wo   = (const u16*)d_in[7];

    const size_t TEN = (size_t)MROWS * D_MODEL;   // 4 Mi elements
    const size_t WEL = (size_t)D_MODEL * D_MODEL; // 1 Mi
    u16* qb  = (u16*)d_ws;        // converted bf16 (convert_all order)
    u16* kb  = qb + TEN;
    u16* vb  = kb + TEN;
    u16* Wqb = vb + TEN;
    u16* Wkb = Wqb + WEL;
    u16* Wvb = Wkb + WEL;
    u16* Wob = Wvb + WEL;
    u16* Qh  = Wob + WEL;         // [B,H,L,HD]
    u16* Kh  = Qh + TEN;
    u16* Vtr = Kh + TEN;          // [B,H,HD,L]
    u16* ctx = Vtr + TEN;         // [B,L,D]

    convert_all<<<dim3(16384), dim3(256), 0, stream>>>(q,k,v,Wq,Wk,Wv,Wo, qb);
    gemm_qkv<<<dim3(8,32,3), dim3(256), 0, stream>>>(qb,kb,vb, Wqb,Wkb,Wvb, Qh,Kh,Vtr);
    attn6<<<dim3(512), dim3(256), 0, stream>>>(Qh, Kh, Vtr, mask, ctx);
    gemm_out<<<dim3(8,64), dim3(256), 0, stream>>>(ctx, Wob, d_out, q);
}